// Round 17
// baseline (326.363 us; speedup 1.0000x reference)
//
#include <hip/hip_runtime.h>
#include <hip/hip_bf16.h>

#define KC   1024
#define DD   256
#define NN   32768
#define HWC  1024
#define LOSS_OFF 8388608
#define IDX_OFF  8388609
#define CBT_OFF  2000000   // cbT[256][1024] in out's x_q region; gather overwrites later

// Replicate numpy pairwise_sum of a[i]*a[i], n=256 (validated: absmax 0.0 r2..r16).
__device__ __forceinline__ float np_pairwise_sumsq_256(const float* __restrict__ a) {
#pragma clang fp contract(off)
  float half0, half1;
  {
    const float* p = a;
    float r[8];
#pragma unroll
    for (int j = 0; j < 8; ++j) r[j] = p[j] * p[j];
    for (int i = 8; i < 128; i += 8) {
#pragma unroll
      for (int j = 0; j < 8; ++j) r[j] = r[j] + p[i + j] * p[i + j];
    }
    half0 = ((r[0] + r[1]) + (r[2] + r[3])) + ((r[4] + r[5]) + (r[6] + r[7]));
  }
  {
    const float* p = a + 128;
    float r[8];
#pragma unroll
    for (int j = 0; j < 8; ++j) r[j] = p[j] * p[j];
    for (int i = 8; i < 128; i += 8) {
#pragma unroll
      for (int j = 0; j < 8; ++j) r[j] = r[j] + p[i + j] * p[i + j];
    }
    half1 = ((r[0] + r[1]) + (r[2] + r[3])) + ((r[4] + r[5]) + (r[6] + r[7]));
  }
  return half0 + half1;
}

// Same chain, element i at a[i*HWC] (bit-identical values/order to the dense
// version — only the addressing differs). Used to compute xsq straight from
// global so the 33KB xs LDS tile can be deleted (it throttled residency).
__device__ __forceinline__ float np_pairwise_sumsq_256_str(const float* __restrict__ a) {
#pragma clang fp contract(off)
  float half0, half1;
  {
    const float* p = a;
    float r[8];
#pragma unroll
    for (int j = 0; j < 8; ++j) { const float v = p[(size_t)j * HWC]; r[j] = v * v; }
    for (int i = 8; i < 128; i += 8) {
#pragma unroll
      for (int j = 0; j < 8; ++j) { const float v = p[(size_t)(i + j) * HWC]; r[j] = r[j] + v * v; }
    }
    half0 = ((r[0] + r[1]) + (r[2] + r[3])) + ((r[4] + r[5]) + (r[6] + r[7]));
  }
  {
    const float* p = a + (size_t)128 * HWC;
    float r[8];
#pragma unroll
    for (int j = 0; j < 8; ++j) { const float v = p[(size_t)j * HWC]; r[j] = v * v; }
    for (int i = 8; i < 128; i += 8) {
#pragma unroll
      for (int j = 0; j < 8; ++j) { const float v = p[(size_t)(i + j) * HWC]; r[j] = r[j] + v * v; }
    }
    half1 = ((r[0] + r[1]) + (r[2] + r[3])) + ((r[4] + r[5]) + (r[6] + r[7]));
  }
  return half0 + half1;
}

// K0: e_sq[k] via numpy-pairwise; zero loss accumulator.
__global__ void vq_esq_kernel(const float* __restrict__ cb, float* __restrict__ esq,
                              float* __restrict__ loss_acc) {
  const int k = blockIdx.x * 256 + threadIdx.x;
  if (k == 0) loss_acc[0] = 0.0f;
  if (k < KC) esq[k] = np_pairwise_sumsq_256(cb + ((size_t)k << 8));
}

// K0b: cbT[d][k] = cb[k][d] (1MB, L2-resident; makes argmin e-loads coalesced).
__global__ __launch_bounds__(256) void vq_transpose_kernel(const float* __restrict__ cb,
                                                           float* __restrict__ cbT) {
  const int d = blockIdx.x;     // 0..255
  const int t = threadIdx.x;
#pragma unroll
  for (int q = 0; q < 4; ++q) {
    const int k = (q << 8) + t;
    cbT[(d << 10) + k] = cb[((size_t)k << 8) + d];
  }
}

// K1: fused distance + argmin — r16's validated structure (16 rows/thread,
// 1024-cyc FMA blocks) with the xs LDS tile DELETED (xsq now computed
// directly from global via the strided pairwise; hot loop never used xs).
// LDS 34.8KB -> ~1.3KB and LB(256,3): recover the residency that the big
// tile throttled (r16 occupancy 21% ~ 1.7 waves/SIMD; chunk-boundary load
// bubbles uncovered). (256,3) is squeeze-safe at natural 88 VGPR (r12).
__global__ __launch_bounds__(256, 3)
void vq_argmin_kernel(const float* __restrict__ x, const float* __restrict__ cbT,
                      const float* __restrict__ esq, int* __restrict__ idxout,
                      float* __restrict__ out) {
  __shared__ float xsq[32];
  __shared__ float rbest[4][32];
  __shared__ int   rbidx[4][32];

  const int tid  = threadIdx.x;
  const int lane = tid & 63;
  const int w    = __builtin_amdgcn_readfirstlane(tid >> 6);  // 0..3, SGPR
  const int ws   = w & 1;             // code half
  const int rh   = w >> 1;            // row half
  const int n0   = blockIdx.x << 5;   // 1024 blocks x 32 rows
  const int b    = n0 >> 10;
  const int hw0  = n0 & 1023;
  const float* __restrict__ xb = x + (size_t)b * (DD * HWC) + hw0;

  // x_sq per row, numpy-pairwise bitwise from global (tie reproduction — the
  // value chain is identical to the validated dense version).
  if (tid < 32) xsq[tid] = np_pairwise_sumsq_256_str(xb + tid);
  __syncthreads();

  const int c0 = (ws << 9) + (lane << 3);          // 8 contiguous codes
  const int r0 = rh << 4;                          // 16 rows (uniform: w is SGPR)
  const float* __restrict__ xru = xb + r0;         // wave-uniform base

  float acc[8][16];                                // [code j][row r]
#pragma unroll
  for (int j = 0; j < 8; ++j)
#pragma unroll
    for (int r = 0; r < 16; ++r) acc[j][r] = 0.0f;

  // 64 chunks x 4 dims. Per chunk: 8 coalesced e-loads (VGPR) + 4 wave-uniform
  // x s_loads (dwordx16, SGPR) + 512 FMA instrs (1024 cyc issue).
  for (int ch = 0; ch < 64; ++ch) {
    const int dbase = ch << 2;

    // x: xa[di][r] = x[b][dbase+di][hw0+r0+r], 16 contiguous floats per dim.
    float xa[4][16];
#pragma unroll
    for (int di = 0; di < 4; ++di) {
      const float* __restrict__ rp = xru + (size_t)(dbase + di) * HWC;
#pragma unroll
      for (int r = 0; r < 16; ++r) xa[di][r] = rp[r];
    }

    // e: ee[di][j] = cbT[dbase+di][c0+j], coalesced float4 pairs.
    float ee[4][8];
#pragma unroll
    for (int di = 0; di < 4; ++di) {
      const float* __restrict__ rp = cbT + ((size_t)(dbase + di) << 10) + c0;
      const float4 a = *(const float4*)rp;
      const float4 bq = *(const float4*)(rp + 4);
      ee[di][0] = a.x;  ee[di][1] = a.y;  ee[di][2] = a.z;  ee[di][3] = a.w;
      ee[di][4] = bq.x; ee[di][5] = bq.y; ee[di][6] = bq.z; ee[di][7] = bq.w;
    }

    // Per-acc chain: dims ascending (di 0..3) — identical order to r13/r16.
#pragma unroll
    for (int r = 0; r < 16; ++r)
#pragma unroll
      for (int j = 0; j < 8; ++j)
#pragma unroll
        for (int di = 0; di < 4; ++di)
          acc[j][r] = fmaf(xa[di][r], ee[di][j], acc[j][r]);
  }

  // esq for 8 contiguous codes: two float4 loads.
  float eq[8];
  {
    const float4 e0 = *(const float4*)(esq + c0);
    const float4 e1 = *(const float4*)(esq + c0 + 4);
    eq[0]=e0.x; eq[1]=e0.y; eq[2]=e0.z; eq[3]=e0.w;
    eq[4]=e1.x; eq[5]=e1.y; eq[6]=e1.z; eq[7]=e1.w;
  }

#pragma unroll
  for (int r = 0; r < 16; ++r) {
    const float xq = xsq[r0 + r];
    float v; int ki;
    {
      // Reference rounding: fl(e_sq - fl(2*dot)) then fl(t + x_sq). No FMA here.
#pragma clang fp contract(off)
      v = (eq[0] - 2.0f * acc[0][r]) + xq; ki = c0;   // ascending j, strict <
#pragma unroll
      for (int j = 1; j < 8; ++j) {
        const float dj = (eq[j] - 2.0f * acc[j][r]) + xq;
        if (dj < v) { v = dj; ki = c0 + j; }
      }
    }
    // Wave-wide (val,idx) min, lowest k on ties.
#pragma unroll
    for (int off = 32; off >= 1; off >>= 1) {
      const float v2 = __shfl_xor(v, off, 64);
      const int   k2 = __shfl_xor(ki, off, 64);
      if (v2 < v || (v2 == v && k2 < ki)) { v = v2; ki = k2; }
    }
    if (lane == 0) { rbest[w][r0 + r] = v; rbidx[w][r0 + r] = ki; }
  }
  __syncthreads();

  // Merge the two code halves per row (ws=0 then ws=1; strict < keeps lowest k).
  if (tid < 32) {
    const int w0 = (tid >> 4) << 1;    // wave with ws=0 for this row's half
    float bb = rbest[w0][tid];
    int   bi = rbidx[w0][tid];
    const float v1 = rbest[w0 + 1][tid];
    if (v1 < bb) { bb = v1; bi = rbidx[w0 + 1][tid]; }
    idxout[n0 + tid] = bi;
    out[IDX_OFF + n0 + tid] = (float)bi;       // fp32 index output
  }
}

// K2: gather codebook rows per block into LDS, write x_q_st (fp32), accumulate loss.
// Overwrites ALL of out's x_q region (including the cbT scratch area).
__global__ __launch_bounds__(256, 2)
void vq_gather_kernel(const float* __restrict__ x, const float* __restrict__ cb,
                      const int* __restrict__ idxin, float* __restrict__ loss_acc,
                      float* __restrict__ out) {
  __shared__ float qs[64][260];
  __shared__ int   idx_s[64];
  __shared__ float wr[4];

  const int tid  = threadIdx.x;
  const int lane = tid & 63;
  const int w    = tid >> 6;
  const int n0   = blockIdx.x << 6;
  const int b    = n0 >> 10;
  const int hw0  = n0 & 1023;

  if (tid < 64) idx_s[tid] = idxin[n0 + tid];
  __syncthreads();

  const float4* __restrict__ cb4 = (const float4*)cb;
  for (int r = w; r < 64; r += 4) {
    const int c = idx_s[r];
    const float4 v = cb4[((size_t)c << 6) + lane];  // coalesced 1KB row read per wave
    *(float4*)&qs[r][lane << 2] = v;
  }
  __syncthreads();

  float lsum = 0.f;
  const size_t obase = (size_t)b * (DD * HWC) + hw0 + lane;
  for (int i = 0; i < 64; ++i) {
    const int d = (w << 6) + i;
    const size_t o = obase + (size_t)d * HWC;
    const float q  = qs[lane][d];
    const float xv = x[o];
    {
#pragma clang fp contract(off)
      const float df = q - xv;           // fl(x_q - x)
      out[o] = xv + df;                  // x_q_st = fl(x + fl(x_q - x)), fp32
      lsum = fmaf(df, df, lsum);         // loss accumulation (loose threshold)
    }
  }

  for (int off = 32; off > 0; off >>= 1) lsum += __shfl_down(lsum, off, 64);
  if (lane == 0) wr[w] = lsum;
  __syncthreads();
  if (tid == 0) atomicAdd(loss_acc, (wr[0] + wr[1]) + (wr[2] + wr[3]));
}

// K3: loss = 1.5 * mean((x_q - x)^2), fp32
__global__ void vq_loss_kernel(const float* __restrict__ loss_acc,
                               float* __restrict__ out) {
  if (threadIdx.x == 0) {
    const float m = loss_acc[0] / 8388608.0f;
    out[LOSS_OFF] = m + 0.5f * m;
  }
}

extern "C" void kernel_launch(void* const* d_in, const int* in_sizes, int n_in,
                              void* d_out, int out_size, void* d_ws, size_t ws_size,
                              hipStream_t stream) {
  const float* x  = (const float*)d_in[0];   // [32,256,32,32] fp32
  const float* cb = (const float*)d_in[1];   // [1024,256] fp32
  float* out = (float*)d_out;                // [x_q_st | loss | indices] fp32

  float* esq      = (float*)d_ws;            // 1024 floats
  float* loss_acc = esq + 1024;              // 1 float (zeroed by K0 each call)
  int*   idxbuf   = (int*)(esq + 1040);      // 32768 ints
  float* cbT      = out + CBT_OFF;           // 256x1024 floats, overwritten by K2

  hipLaunchKernelGGL(vq_esq_kernel,       dim3(4),    dim3(256), 0, stream, cb, esq, loss_acc);
  hipLaunchKernelGGL(vq_transpose_kernel, dim3(256),  dim3(256), 0, stream, cb, cbT);
  hipLaunchKernelGGL(vq_argmin_kernel,    dim3(1024), dim3(256), 0, stream, x, cbT, esq, idxbuf, out);
  hipLaunchKernelGGL(vq_gather_kernel,    dim3(512),  dim3(256), 0, stream, x, cb, idxbuf, loss_acc, out);
  hipLaunchKernelGGL(vq_loss_kernel,      dim3(1),    dim3(64),  0, stream, loss_acc, out);
}

// Round 18
// 218.601 us; speedup vs baseline: 1.4930x; 1.4930x over previous
//
#include <hip/hip_runtime.h>
#include <hip/hip_bf16.h>

#define KC   1024
#define DD   256
#define NN   32768
#define HWC  1024
#define LOSS_OFF 8388608
#define IDX_OFF  8388609
#define CBT_OFF  2000000   // cbT[256][1024] in out's x_q region; gather overwrites later

// Replicate numpy pairwise_sum of a[i]*a[i], n=256 (validated: absmax 0.0 r2..r16).
__device__ __forceinline__ float np_pairwise_sumsq_256(const float* __restrict__ a) {
#pragma clang fp contract(off)
  float half0, half1;
  {
    const float* p = a;
    float r[8];
#pragma unroll
    for (int j = 0; j < 8; ++j) r[j] = p[j] * p[j];
    for (int i = 8; i < 128; i += 8) {
#pragma unroll
      for (int j = 0; j < 8; ++j) r[j] = r[j] + p[i + j] * p[i + j];
    }
    half0 = ((r[0] + r[1]) + (r[2] + r[3])) + ((r[4] + r[5]) + (r[6] + r[7]));
  }
  {
    const float* p = a + 128;
    float r[8];
#pragma unroll
    for (int j = 0; j < 8; ++j) r[j] = p[j] * p[j];
    for (int i = 8; i < 128; i += 8) {
#pragma unroll
      for (int j = 0; j < 8; ++j) r[j] = r[j] + p[i + j] * p[i + j];
    }
    half1 = ((r[0] + r[1]) + (r[2] + r[3])) + ((r[4] + r[5]) + (r[6] + r[7]));
  }
  return half0 + half1;
}

// K0: e_sq[k] via numpy-pairwise; zero loss accumulator.
__global__ void vq_esq_kernel(const float* __restrict__ cb, float* __restrict__ esq,
                              float* __restrict__ loss_acc) {
  const int k = blockIdx.x * 256 + threadIdx.x;
  if (k == 0) loss_acc[0] = 0.0f;
  if (k < KC) esq[k] = np_pairwise_sumsq_256(cb + ((size_t)k << 8));
}

// K0b: cbT[d][k] = cb[k][d] (1MB, L2-resident; makes argmin e-loads coalesced).
__global__ __launch_bounds__(256) void vq_transpose_kernel(const float* __restrict__ cb,
                                                           float* __restrict__ cbT) {
  const int d = blockIdx.x;     // 0..255
  const int t = threadIdx.x;
#pragma unroll
  for (int q = 0; q < 4; ++q) {
    const int k = (q << 8) + t;
    cbT[(d << 10) + k] = cb[((size_t)k << 8) + d];
  }
}

// K1: fused distance + argmin — r16's hot loop UNCHANGED (16 rows/thread,
// 1024-cyc FMA blocks, 222us). Only the xsq prologue is re-implemented:
// STREAMED staging in four 32x64 sub-tiles (xs[32][68] = 8.7KB, was 33KB).
// The numpy pairwise chain consumes dims in order with 8 accumulators, so the
// partial r[8] advances across sub-tiles in registers — bit-identical xsq.
// (r17 lesson: computing xsq from strided GLOBAL serialized the prologue —
// ~180us of exposed latency on 32 lanes; staging must stay LDS+cooperative.)
// LDS 34.8KB -> ~10.5KB recovers r13-class residency with r16's loop.
__global__ __launch_bounds__(256, 2)
void vq_argmin_kernel(const float* __restrict__ x, const float* __restrict__ cbT,
                      const float* __restrict__ esq, int* __restrict__ idxout,
                      float* __restrict__ out) {
  __shared__ float xs[32][68];     // 32 rows x 64-dim sub-tile (+pad)
  __shared__ float xsq[32];
  __shared__ float rbest[4][32];
  __shared__ int   rbidx[4][32];

  const int tid  = threadIdx.x;
  const int lane = tid & 63;
  const int w    = __builtin_amdgcn_readfirstlane(tid >> 6);  // 0..3, SGPR
  const int ws   = w & 1;             // code half
  const int rh   = w >> 1;            // row half
  const int n0   = blockIdx.x << 5;   // 1024 blocks x 32 rows
  const int b    = n0 >> 10;
  const int hw0  = n0 & 1023;
  const float* __restrict__ xb = x + (size_t)b * (DD * HWC) + hw0;

  // ---- xsq prologue: streamed numpy-pairwise (bit-identical chain) ----
  {
    const int rr = tid & 31;
    const int dq = tid >> 5;          // 0..7 -> 8 dims each per sub-tile
    float r8[8];
    float half0 = 0.0f, half1 = 0.0f;
#pragma unroll
    for (int s = 0; s < 4; ++s) {     // sub-tile s covers dims s*64..s*64+63
      // cooperative staging, coalesced 128B segments
#pragma unroll
      for (int i = 0; i < 8; ++i) {
        const int dl = (dq << 3) + i;
        const int d  = (s << 6) + dl;
        xs[rr][dl] = xb[(size_t)d * HWC + rr];
      }
      __syncthreads();
      if (tid < 32) {
#pragma clang fp contract(off)
        const float* __restrict__ p = &xs[tid][0];
        if ((s & 1) == 0) {           // dims 0..7 of a 128-half: init r8
#pragma unroll
          for (int j = 0; j < 8; ++j) r8[j] = p[j] * p[j];
          for (int i = 8; i < 64; i += 8)
#pragma unroll
            for (int j = 0; j < 8; ++j) r8[j] = r8[j] + p[i + j] * p[i + j];
        } else {                      // second 64 dims of the 128-half
          for (int i = 0; i < 64; i += 8)
#pragma unroll
            for (int j = 0; j < 8; ++j) r8[j] = r8[j] + p[i + j] * p[i + j];
          const float h = ((r8[0] + r8[1]) + (r8[2] + r8[3])) +
                          ((r8[4] + r8[5]) + (r8[6] + r8[7]));
          if (s == 1) half0 = h; else half1 = h;
        }
      }
      __syncthreads();
    }
    if (tid < 32) xsq[tid] = half0 + half1;
  }
  __syncthreads();

  const int c0 = (ws << 9) + (lane << 3);          // 8 contiguous codes
  const int r0 = rh << 4;                          // 16 rows (uniform: w is SGPR)
  const float* __restrict__ xru = xb + r0;         // wave-uniform base

  float acc[8][16];                                // [code j][row r]
#pragma unroll
  for (int j = 0; j < 8; ++j)
#pragma unroll
    for (int r = 0; r < 16; ++r) acc[j][r] = 0.0f;

  // 64 chunks x 4 dims. Per chunk: 8 coalesced e-loads (VGPR) + 4 wave-uniform
  // x s_loads (dwordx16, SGPR) + 512 FMA instrs (1024 cyc issue).
  for (int ch = 0; ch < 64; ++ch) {
    const int dbase = ch << 2;

    float xa[4][16];
#pragma unroll
    for (int di = 0; di < 4; ++di) {
      const float* __restrict__ rp = xru + (size_t)(dbase + di) * HWC;
#pragma unroll
      for (int r = 0; r < 16; ++r) xa[di][r] = rp[r];
    }

    float ee[4][8];
#pragma unroll
    for (int di = 0; di < 4; ++di) {
      const float* __restrict__ rp = cbT + ((size_t)(dbase + di) << 10) + c0;
      const float4 a = *(const float4*)rp;
      const float4 bq = *(const float4*)(rp + 4);
      ee[di][0] = a.x;  ee[di][1] = a.y;  ee[di][2] = a.z;  ee[di][3] = a.w;
      ee[di][4] = bq.x; ee[di][5] = bq.y; ee[di][6] = bq.z; ee[di][7] = bq.w;
    }

    // Per-acc chain: dims ascending (di 0..3) — identical order to r13/r16.
#pragma unroll
    for (int r = 0; r < 16; ++r)
#pragma unroll
      for (int j = 0; j < 8; ++j)
#pragma unroll
        for (int di = 0; di < 4; ++di)
          acc[j][r] = fmaf(xa[di][r], ee[di][j], acc[j][r]);
  }

  // esq for 8 contiguous codes: two float4 loads.
  float eq[8];
  {
    const float4 e0 = *(const float4*)(esq + c0);
    const float4 e1 = *(const float4*)(esq + c0 + 4);
    eq[0]=e0.x; eq[1]=e0.y; eq[2]=e0.z; eq[3]=e0.w;
    eq[4]=e1.x; eq[5]=e1.y; eq[6]=e1.z; eq[7]=e1.w;
  }

#pragma unroll
  for (int r = 0; r < 16; ++r) {
    const float xq = xsq[r0 + r];
    float v; int ki;
    {
      // Reference rounding: fl(e_sq - fl(2*dot)) then fl(t + x_sq). No FMA here.
#pragma clang fp contract(off)
      v = (eq[0] - 2.0f * acc[0][r]) + xq; ki = c0;   // ascending j, strict <
#pragma unroll
      for (int j = 1; j < 8; ++j) {
        const float dj = (eq[j] - 2.0f * acc[j][r]) + xq;
        if (dj < v) { v = dj; ki = c0 + j; }
      }
    }
    // Wave-wide (val,idx) min, lowest k on ties.
#pragma unroll
    for (int off = 32; off >= 1; off >>= 1) {
      const float v2 = __shfl_xor(v, off, 64);
      const int   k2 = __shfl_xor(ki, off, 64);
      if (v2 < v || (v2 == v && k2 < ki)) { v = v2; ki = k2; }
    }
    if (lane == 0) { rbest[w][r0 + r] = v; rbidx[w][r0 + r] = ki; }
  }
  __syncthreads();

  // Merge the two code halves per row (ws=0 then ws=1; strict < keeps lowest k).
  if (tid < 32) {
    const int w0 = (tid >> 4) << 1;    // wave with ws=0 for this row's half
    float bb = rbest[w0][tid];
    int   bi = rbidx[w0][tid];
    const float v1 = rbest[w0 + 1][tid];
    if (v1 < bb) { bb = v1; bi = rbidx[w0 + 1][tid]; }
    idxout[n0 + tid] = bi;
    out[IDX_OFF + n0 + tid] = (float)bi;       // fp32 index output
  }
}

// K2: gather codebook rows per block into LDS, write x_q_st (fp32), accumulate loss.
// Overwrites ALL of out's x_q region (including the cbT scratch area).
__global__ __launch_bounds__(256, 2)
void vq_gather_kernel(const float* __restrict__ x, const float* __restrict__ cb,
                      const int* __restrict__ idxin, float* __restrict__ loss_acc,
                      float* __restrict__ out) {
  __shared__ float qs[64][260];
  __shared__ int   idx_s[64];
  __shared__ float wr[4];

  const int tid  = threadIdx.x;
  const int lane = tid & 63;
  const int w    = tid >> 6;
  const int n0   = blockIdx.x << 6;
  const int b    = n0 >> 10;
  const int hw0  = n0 & 1023;

  if (tid < 64) idx_s[tid] = idxin[n0 + tid];
  __syncthreads();

  const float4* __restrict__ cb4 = (const float4*)cb;
  for (int r = w; r < 64; r += 4) {
    const int c = idx_s[r];
    const float4 v = cb4[((size_t)c << 6) + lane];  // coalesced 1KB row read per wave
    *(float4*)&qs[r][lane << 2] = v;
  }
  __syncthreads();

  float lsum = 0.f;
  const size_t obase = (size_t)b * (DD * HWC) + hw0 + lane;
  for (int i = 0; i < 64; ++i) {
    const int d = (w << 6) + i;
    const size_t o = obase + (size_t)d * HWC;
    const float q  = qs[lane][d];
    const float xv = x[o];
    {
#pragma clang fp contract(off)
      const float df = q - xv;           // fl(x_q - x)
      out[o] = xv + df;                  // x_q_st = fl(x + fl(x_q - x)), fp32
      lsum = fmaf(df, df, lsum);         // loss accumulation (loose threshold)
    }
  }

  for (int off = 32; off > 0; off >>= 1) lsum += __shfl_down(lsum, off, 64);
  if (lane == 0) wr[w] = lsum;
  __syncthreads();
  if (tid == 0) atomicAdd(loss_acc, (wr[0] + wr[1]) + (wr[2] + wr[3]));
}

// K3: loss = 1.5 * mean((x_q - x)^2), fp32
__global__ void vq_loss_kernel(const float* __restrict__ loss_acc,
                               float* __restrict__ out) {
  if (threadIdx.x == 0) {
    const float m = loss_acc[0] / 8388608.0f;
    out[LOSS_OFF] = m + 0.5f * m;
  }
}

extern "C" void kernel_launch(void* const* d_in, const int* in_sizes, int n_in,
                              void* d_out, int out_size, void* d_ws, size_t ws_size,
                              hipStream_t stream) {
  const float* x  = (const float*)d_in[0];   // [32,256,32,32] fp32
  const float* cb = (const float*)d_in[1];   // [1024,256] fp32
  float* out = (float*)d_out;                // [x_q_st | loss | indices] fp32

  float* esq      = (float*)d_ws;            // 1024 floats
  float* loss_acc = esq + 1024;              // 1 float (zeroed by K0 each call)
  int*   idxbuf   = (int*)(esq + 1040);      // 32768 ints
  float* cbT      = out + CBT_OFF;           // 256x1024 floats, overwritten by K2

  hipLaunchKernelGGL(vq_esq_kernel,       dim3(4),    dim3(256), 0, stream, cb, esq, loss_acc);
  hipLaunchKernelGGL(vq_transpose_kernel, dim3(256),  dim3(256), 0, stream, cb, cbT);
  hipLaunchKernelGGL(vq_argmin_kernel,    dim3(1024), dim3(256), 0, stream, x, cbT, esq, idxbuf, out);
  hipLaunchKernelGGL(vq_gather_kernel,    dim3(512),  dim3(256), 0, stream, x, cb, idxbuf, loss_acc, out);
  hipLaunchKernelGGL(vq_loss_kernel,      dim3(1),    dim3(64),  0, stream, loss_acc, out);
}